// Round 8
// baseline (4426.752 us; speedup 1.0000x reference)
//
#include <hip/hip_runtime.h>
#include <hip/hip_bf16.h>

typedef unsigned short ushort_t;
typedef unsigned int uint_t;
typedef unsigned long long u64_t;

typedef __attribute__((ext_vector_type(8))) short bf16x8;   // 8 bf16 (4 VGPRs)
typedef __attribute__((ext_vector_type(4))) float floatx4;  // MFMA C/D

#define DI __device__ __forceinline__

// record: bits[0..17)=src (N<131072), bits[17..23)=dst&63, bits[32..64)=|w| f32
#define NPB 64           // nodes per bucket
#define NBMAX 2048       // max buckets
#define CH 8             // src chunks (src>>14); xw slice = 16384*192B = 3.1MB < 4MB L2/XCD

// bf16 bits -> f32
DI float b2f(uint_t lo16) {
    union { uint_t u; float f; } v; v.u = lo16 << 16; return v.f;
}
// f32 -> bf16 bits, round-to-nearest-even
DI ushort_t f2b(float f) {
    union { float f; uint_t u; } v; v.f = f;
    uint_t u = v.u;
    uint_t r = (u + 0x7fffu + ((u >> 16) & 1u)) >> 16;
    return (ushort_t)r;
}

// ---------------- P1: bucket histogram (LDS-binned; ~150k global atomics) ----
__global__ __launch_bounds__(1024) void gcn_bhist(
    const int* __restrict__ ei, int* __restrict__ bkt_cnt, int E, int NB)
{
    __shared__ int hist[NBMAX];
    int t = threadIdx.x;
    for (int b = t; b < NB; b += 1024) hist[b] = 0;
    __syncthreads();
    int base = blockIdx.x * 32768;
    int lim = min(32768, E - base);
    for (int i = t; i < lim; i += 1024) {
        int d = ei[(size_t)E + base + i];
        atomicAdd(&hist[d >> 6], 1);
    }
    __syncthreads();
    for (int b = t; b < NB; b += 1024) {
        int c = hist[b];
        if (c) atomicAdd(&bkt_cnt[b], c);
    }
}

// ---------------- P2: scan bucket counts -> bases/cursors (8 per thread) -----
__global__ __launch_bounds__(256) void gcn_bscan(
    const int* __restrict__ bkt_cnt, int* __restrict__ bkt_base,
    int* __restrict__ bkt_cursor, int NB, int E)
{
    __shared__ int lds[256];
    int t = threadIdx.x;
    int v[8]; int s = 0;
    #pragma unroll
    for (int j = 0; j < 8; j++) {
        int b = t * 8 + j;
        v[j] = (b < NB) ? bkt_cnt[b] : 0;
        s += v[j];
    }
    lds[t] = s;
    __syncthreads();
    #pragma unroll
    for (int off = 1; off < 256; off <<= 1) {
        int y = (t >= off) ? lds[t - off] : 0;
        __syncthreads();
        lds[t] += y;
        __syncthreads();
    }
    int run = lds[t] - s;
    #pragma unroll
    for (int j = 0; j < 8; j++) {
        int b = t * 8 + j;
        if (b < NB) { bkt_base[b] = run; bkt_cursor[b] = run; }
        run += v[j];
    }
    if (t == 255) bkt_base[NB] = E;
}

// ---------------- P3: scatter records into bucket regions --------------------
__global__ __launch_bounds__(1024) void gcn_bscatter(
    const int* __restrict__ ei, const float* __restrict__ ew,
    int* __restrict__ bkt_cursor, u64_t* __restrict__ stage, int E, int NB)
{
    __shared__ int hist[NBMAX];
    __shared__ int cur[NBMAX];
    int t = threadIdx.x;
    for (int b = t; b < NB; b += 1024) hist[b] = 0;
    __syncthreads();
    int base = blockIdx.x * 32768;
    int lim = min(32768, E - base);
    for (int i = t; i < lim; i += 1024) {
        int d = ei[(size_t)E + base + i];
        atomicAdd(&hist[d >> 6], 1);
    }
    __syncthreads();
    for (int b = t; b < NB; b += 1024) {
        int c = hist[b];
        cur[b] = c ? atomicAdd(&bkt_cursor[b], c) : 0;
    }
    __syncthreads();
    for (int i = t; i < lim; i += 1024) {
        int e = base + i;
        int s = ei[e];
        int d = ei[(size_t)E + e];
        float w = fabsf(ew[e]);
        int pos = atomicAdd(&cur[d >> 6], 1);
        u64_t rec = (u64_t)__float_as_uint(w) << 32
                  | (uint_t)s | ((uint_t)(d & 63) << 17);
        stage[pos] = rec;
    }
}

// ---------------- P4: per-bucket chunk sort (8 bins) + wsum -> dis -----------
__global__ __launch_bounds__(256) void gcn_bchsort(
    const u64_t* __restrict__ stage, u64_t* __restrict__ edges,
    const int* __restrict__ bkt_base, float* __restrict__ dis, int N)
{
    __shared__ int cnt8[8];
    __shared__ int cur8[8];
    __shared__ float wsum[NPB];
    int b = blockIdx.x, t = threadIdx.x;
    if (t < 8) cnt8[t] = 0;
    if (t < NPB) wsum[t] = 0.0f;
    __syncthreads();
    int base = bkt_base[b], end = bkt_base[b + 1];
    for (int i = base + t; i < end; i += 256) {
        u64_t r = stage[i];
        int ch = (int)(((uint_t)r & 0x1FFFFu) >> 14);
        atomicAdd(&cnt8[ch], 1);
        atomicAdd(&wsum[((uint_t)r >> 17) & 63u], __uint_as_float((uint_t)(r >> 32)));
    }
    __syncthreads();
    if (t == 0) {
        int run = base;
        #pragma unroll
        for (int c = 0; c < 8; c++) { cur8[c] = run; run += cnt8[c]; }
    }
    if (t < NPB) {
        int n = (b << 6) + t;
        if (n < N) dis[n] = rsqrtf(wsum[t] + 1.0f);
    }
    __syncthreads();
    for (int i = base + t; i < end; i += 256) {
        u64_t r = stage[i];
        int ch = (int)(((uint_t)r & 0x1FFFFu) >> 14);
        int pos = atomicAdd(&cur8[ch], 1);
        edges[pos] = r;
    }
}

// ---------------- weight transpose + bf16 convert (once per call, tiny) -------
__global__ __launch_bounds__(256) void gcn_wt(
    const float* __restrict__ W1, const float* __restrict__ W2,
    const float* __restrict__ W3,
    ushort_t* __restrict__ Wt1, ushort_t* __restrict__ Wt2,
    ushort_t* __restrict__ Wt3)
{
    int i = blockIdx.x * 256 + threadIdx.x;
    if (i < 96 * 128) {                       // layer 1: Wt1[96][128]
        int n = i / 128, k = i % 128;
        Wt1[i] = f2b(W1[k * 96 + n]);
    }
    if (i < 96 * 96) {                        // layer 2: Wt2[96][96]
        int n = i / 96, k = i % 96;
        Wt2[i] = f2b(W2[k * 96 + n]);
    }
    if (i < 32 * 96) {                        // layer 3: Wt3[32][96], pad rows 30,31
        int n = i / 96, k = i % 96;
        Wt3[i] = f2b((n < 30) ? W3[k * 30 + n] : 0.0f);
    }
}

// ---------------- MFMA GEMM: Y[row,:] = dis[row] * (X[row,:] @ W) ------------
template<int K, int FOUT, int NTR, int FOUTP, bool XF32>
__global__ __launch_bounds__(256) void gcn_gemm_mfma(
    const void* __restrict__ Xv, const ushort_t* __restrict__ Wt,
    const float* __restrict__ dis, ushort_t* __restrict__ Y, int N)
{
    constexpr int KS = K + 8;
    constexpr int KT = K / 32;
    constexpr int NT = NTR / 16;
    __shared__ ushort_t xs[64 * KS];
    __shared__ ushort_t ws[NTR * KS];

    int t = threadIdx.x;
    int mbase = blockIdx.x * 64;

    {
        constexpr int TOT = NTR * (K / 8);
        const uint4* wg = (const uint4*)Wt;
        for (int i = t; i < TOT; i += 256) {
            int r = i / (K / 8), c8 = i % (K / 8);
            *(uint4*)(ws + r * KS + c8 * 8) = wg[i];
        }
    }
    if (XF32) {
        const float* X = (const float*)Xv;
        constexpr int TOT = 64 * (K / 4);
        for (int i = t; i < TOT; i += 256) {
            int row = i / (K / 4), c4 = i % (K / 4);
            int rg = mbase + row; if (rg >= N) rg = N - 1;
            float4 v = *(const float4*)(X + (size_t)rg * K + c4 * 4);
            uint2 pv;
            pv.x = (uint_t)f2b(v.x) | ((uint_t)f2b(v.y) << 16);
            pv.y = (uint_t)f2b(v.z) | ((uint_t)f2b(v.w) << 16);
            *(uint2*)(xs + row * KS + c4 * 4) = pv;
        }
    } else {
        const ushort_t* X = (const ushort_t*)Xv;
        constexpr int TOT = 64 * (K / 8);
        for (int i = t; i < TOT; i += 256) {
            int row = i / (K / 8), c8 = i % (K / 8);
            int rg = mbase + row; if (rg >= N) rg = N - 1;
            *(uint4*)(xs + row * KS + c8 * 8) = *(const uint4*)(X + (size_t)rg * K + c8 * 8);
        }
    }
    __syncthreads();

    int wave = t >> 6;
    int lane = t & 63;
    int l15 = lane & 15, quad = lane >> 4;

    bf16x8 af[KT];
    #pragma unroll
    for (int kt = 0; kt < KT; kt++)
        af[kt] = *(const bf16x8*)(xs + (wave * 16 + l15) * KS + kt * 32 + quad * 8);

    floatx4 acc[NT];
    #pragma unroll
    for (int nt = 0; nt < NT; nt++) acc[nt] = (floatx4){0.f, 0.f, 0.f, 0.f};

    #pragma unroll
    for (int nt = 0; nt < NT; nt++) {
        #pragma unroll
        for (int kt = 0; kt < KT; kt++) {
            bf16x8 bfr = *(const bf16x8*)(ws + (nt * 16 + l15) * KS + kt * 32 + quad * 8);
            acc[nt] = __builtin_amdgcn_mfma_f32_16x16x32_bf16(af[kt], bfr, acc[nt], 0, 0, 0);
        }
    }

    float dsc[4];
    #pragma unroll
    for (int r = 0; r < 4; r++) {
        int row = mbase + wave * 16 + quad * 4 + r;
        dsc[r] = (row < N) ? dis[row] : 0.0f;
    }
    #pragma unroll
    for (int nt = 0; nt < NT; nt++) {
        int col = nt * 16 + l15;
        #pragma unroll
        for (int r = 0; r < 4; r++) {
            int row = mbase + wave * 16 + quad * 4 + r;
            if (row < N) {
                float v = (col < FOUT) ? acc[nt][r] * dsc[r] : 0.0f;
                Y[(size_t)row * FOUTP + col] = f2b(v);
            }
        }
    }
}

// ---------------- aggregation: bucket-owner, LDS fp32 accumulators ------------
// Edges are (bucket, chunk)-sorted; all blocks co-resident sweep their segments
// linearly -> statistically phase-coherent gathers over the same ~3MB xw slice
// (per-XCD L2 resident). Lane-per-edge: 64 independent gathers/wave in flight.
// STR: LDS row stride (97/33) -> ds_add banks spread; per-lane feature phase
// rotation avoids same-address collisions on dstl runs.
// H[n] = relu(b + dis[n]*(sum_e w*XWS[src] + XWS[n])), XWS = dis-scaled xw.
template<int FOUT, int FOUTP, int STR>
__global__ __launch_bounds__(256) void gcn_agg_lds(
    const ushort_t* __restrict__ XWS, const u64_t* __restrict__ edges,
    const int* __restrict__ bkt_base, const float* __restrict__ dis,
    const float* __restrict__ bias, ushort_t* __restrict__ H, int N)
{
    constexpr int NC = FOUTP / 8;           // uint4 per feature row
    __shared__ float acc[NPB * STR];
    int t = threadIdx.x;
    int b = blockIdx.x;
    for (int i = t; i < NPB * STR; i += 256) acc[i] = 0.0f;
    __syncthreads();

    int base = bkt_base[b], end = bkt_base[b + 1];
    const uint4* xwc = (const uint4*)XWS;
    int ph = (t & 63) % NC;

    for (int e = base + t; e < end; e += 256) {
        u64_t r = __builtin_nontemporal_load(edges + e);
        int src = (int)((uint_t)r & 0x1FFFFu);
        int dl  = (int)(((uint_t)r >> 17) & 63u);
        float w = __uint_as_float((uint_t)(r >> 32));
        const uint4* row = xwc + (size_t)src * NC;
        float* arow = acc + dl * STR;
        #pragma unroll
        for (int cc = 0; cc < NC; cc++) {
            int c = cc + ph; if (c >= NC) c -= NC;
            uint4 v = row[c];
            float* ap = arow + c * 8;
            atomicAdd(ap + 0, w * b2f(v.x & 0xffffu));
            atomicAdd(ap + 1, w * b2f(v.x >> 16));
            atomicAdd(ap + 2, w * b2f(v.y & 0xffffu));
            atomicAdd(ap + 3, w * b2f(v.y >> 16));
            atomicAdd(ap + 4, w * b2f(v.z & 0xffffu));
            atomicAdd(ap + 5, w * b2f(v.z >> 16));
            atomicAdd(ap + 6, w * b2f(v.w & 0xffffu));
            atomicAdd(ap + 7, w * b2f(v.w >> 16));
        }
    }
    __syncthreads();

    int n0 = b << 6;
    for (int u = t; u < NPB * NC; u += 256) {
        int nl = u / NC, c = u % NC;
        int n = n0 + nl;
        if (n >= N) continue;
        uint4 sv = xwc[(size_t)n * NC + c];
        float d = dis[n];
        const float* ap = acc + nl * STR + c * 8;
        uint_t pv[4] = {sv.x, sv.y, sv.z, sv.w};
        uint_t o[4];
        #pragma unroll
        for (int p = 0; p < 4; p++) {
            int f = c * 8 + 2 * p;
            int fA = (f     < FOUT) ? f     : 0;
            int fB = (f + 1 < FOUT) ? f + 1 : 0;
            float rA = fmaxf(d * (ap[2 * p]     + b2f(pv[p] & 0xffffu)) + bias[fA], 0.f);
            float rB = fmaxf(d * (ap[2 * p + 1] + b2f(pv[p] >> 16))     + bias[fB], 0.f);
            if (f     >= FOUT) rA = 0.f;
            if (f + 1 >= FOUT) rB = 0.f;
            o[p] = (uint_t)f2b(rA) | ((uint_t)f2b(rB) << 16);
        }
        uint4 ov = {o[0], o[1], o[2], o[3]};
        *((uint4*)H + (size_t)n * NC + c) = ov;
    }
}

// ---------------- mean-pool per graph + final linear + softmax ----------------
__global__ __launch_bounds__(256) void gcn_pool(
    const ushort_t* __restrict__ H, const int* __restrict__ batch,
    const float* __restrict__ Wf, const float* __restrict__ bf_,
    float* __restrict__ out, int N)
{
    __shared__ float pool[32];
    int g = blockIdx.x;
    int t = threadIdx.x;

    int lo = 0, hi = N;
    while (lo < hi) { int mid = (lo + hi) >> 1; if (batch[mid] < g) lo = mid + 1; else hi = mid; }
    int start = lo;
    lo = 0; hi = N;
    while (lo < hi) { int mid = (lo + hi) >> 1; if (batch[mid] < g + 1) lo = mid + 1; else hi = mid; }
    int end = lo;

    float acc[32];
    #pragma unroll
    for (int f = 0; f < 32; f++) acc[f] = 0.0f;
    for (int i = start + t; i < end; i += 256) {
        const uint2* hr = (const uint2*)H + (size_t)i * 8;
        #pragma unroll
        for (int q = 0; q < 8; q++) {
            uint2 v = hr[q];
            acc[4 * q + 0] += b2f(v.x & 0xffffu);
            acc[4 * q + 1] += b2f(v.x >> 16);
            acc[4 * q + 2] += b2f(v.y & 0xffffu);
            acc[4 * q + 3] += b2f(v.y >> 16);
        }
    }
    #pragma unroll
    for (int f = 0; f < 32; f++) {
        float v = acc[f];
        v += __shfl_down(v, 32, 64);
        v += __shfl_down(v, 16, 64);
        v += __shfl_down(v, 8, 64);
        v += __shfl_down(v, 4, 64);
        v += __shfl_down(v, 2, 64);
        v += __shfl_down(v, 1, 64);
        acc[f] = v;
    }
    if (t < 32) pool[t] = 0.0f;
    __syncthreads();
    if ((t & 63) == 0) {
        #pragma unroll
        for (int f = 0; f < 30; f++) atomicAdd(&pool[f], acc[f]);
    }
    __syncthreads();
    if (t == 0) {
        float inv = 1.0f / fmaxf((float)(end - start), 1.0f);
        float lg[10];
        #pragma unroll
        for (int j = 0; j < 10; j++) lg[j] = bf_[j];
        for (int f = 0; f < 30; f++) {
            float p = pool[f] * inv;
            #pragma unroll
            for (int j = 0; j < 10; j++) lg[j] += p * Wf[f * 10 + j];
        }
        float m = lg[0];
        #pragma unroll
        for (int j = 1; j < 10; j++) m = fmaxf(m, lg[j]);
        float s = 0.f;
        #pragma unroll
        for (int j = 0; j < 10; j++) { lg[j] = __expf(lg[j] - m); s += lg[j]; }
        float is = 1.0f / s;
        #pragma unroll
        for (int j = 0; j < 10; j++) out[g * 10 + j] = lg[j] * is;
    }
}

extern "C" void kernel_launch(void* const* d_in, const int* in_sizes, int n_in,
                              void* d_out, int out_size, void* d_ws, size_t ws_size,
                              hipStream_t stream) {
    (void)n_in; (void)out_size; (void)ws_size;
    const float* x   = (const float*)d_in[0];
    const int*   ei  = (const int*)d_in[1];
    const float* ew  = (const float*)d_in[2];
    const int*   bat = (const int*)d_in[3];
    const float* W1  = (const float*)d_in[4];
    const float* b1  = (const float*)d_in[5];
    const float* W2  = (const float*)d_in[6];
    const float* b2  = (const float*)d_in[7];
    const float* W3  = (const float*)d_in[8];
    const float* b3  = (const float*)d_in[9];
    const float* Wf  = (const float*)d_in[10];
    const float* bf_ = (const float*)d_in[11];
    float* out = (float*)d_out;

    const int N = in_sizes[3];       // 100000
    const int E = in_sizes[2];       // 3200000
    const int NB = (N + NPB - 1) / NPB;   // 1563

    char* wsb = (char*)d_ws;
    size_t o = 0;
    auto take = [&](size_t bytes) -> char* {
        char* p = wsb + o;
        o += (bytes + 255) & ~(size_t)255;
        return p;
    };
    int*      bkt_cnt    = (int*)take(NBMAX * 4);             // zeroed each call
    int*      bkt_base   = (int*)take((NBMAX + 1) * 4);
    int*      bkt_cursor = (int*)take(NBMAX * 4);
    float*    dis        = (float*)take((size_t)N * 4);
    u64_t*    stage      = (u64_t*)take((size_t)E * 8);       // dead after bchsort; xw aliases it
    u64_t*    edges      = (u64_t*)take((size_t)E * 8);
    ushort_t* h          = (ushort_t*)take((size_t)N * 96 * 2);
    ushort_t* Wt1        = (ushort_t*)take(96 * 128 * 2);
    ushort_t* Wt2        = (ushort_t*)take(96 * 96 * 2);
    ushort_t* Wt3        = (ushort_t*)take(32 * 96 * 2);
    ushort_t* xw         = (ushort_t*)stage;                  // alias (E*8 >= N*96*2)

    const int gB = (E + 32767) / 32768;       // 98
    const int gM = (N + 63) / 64;

    hipMemsetAsync(bkt_cnt, 0, NBMAX * 4, stream);

    // CSR build: bucket hist -> scan -> scatter -> per-bucket chunk sort (+dis)
    gcn_bhist<<<gB, 1024, 0, stream>>>(ei, bkt_cnt, E, NB);
    gcn_wt<<<48, 256, 0, stream>>>(W1, W2, W3, Wt1, Wt2, Wt3);
    gcn_bscan<<<1, 256, 0, stream>>>(bkt_cnt, bkt_base, bkt_cursor, NB, E);
    gcn_bscatter<<<gB, 1024, 0, stream>>>(ei, ew, bkt_cursor, stage, E, NB);
    gcn_bchsort<<<NB, 256, 0, stream>>>(stage, edges, bkt_base, dis, N);

    // layer 1: x[.,128](fp32) -> xws[.,96](bf16, dis-scaled) -> h[.,96](bf16)
    gcn_gemm_mfma<128, 96, 96, 96, true><<<gM, 256, 0, stream>>>(x, Wt1, dis, xw, N);
    gcn_agg_lds<96, 96, 97><<<NB, 256, 0, stream>>>(xw, edges, bkt_base, dis, b1, h, N);

    // layer 2
    gcn_gemm_mfma<96, 96, 96, 96, false><<<gM, 256, 0, stream>>>(h, Wt2, dis, xw, N);
    gcn_agg_lds<96, 96, 97><<<NB, 256, 0, stream>>>(xw, edges, bkt_base, dis, b2, h, N);

    // layer 3 (FOUT=30 padded to 32)
    gcn_gemm_mfma<96, 30, 32, 32, false><<<gM, 256, 0, stream>>>(h, Wt3, dis, xw, N);
    gcn_agg_lds<30, 32, 33><<<NB, 256, 0, stream>>>(xw, edges, bkt_base, dis, b3, h, N);

    // mean pool + classifier + softmax
    gcn_pool<<<256, 256, 0, stream>>>(h, bat, Wf, bf_, out, N);
}

// Round 9
// 899.526 us; speedup vs baseline: 4.9212x; 4.9212x over previous
//
#include <hip/hip_runtime.h>
#include <hip/hip_bf16.h>

typedef unsigned short ushort_t;
typedef unsigned int uint_t;
typedef unsigned long long u64_t;

typedef __attribute__((ext_vector_type(8))) short bf16x8;   // 8 bf16 (4 VGPRs)
typedef __attribute__((ext_vector_type(4))) float floatx4;  // MFMA C/D

#define DI __device__ __forceinline__

// NOTE: record packing uses 17 bits for src -> requires N < 131072. (N=100000)
#define NPB 128          // nodes per bucket
#define NBMAX 1024       // max buckets (N <= 131072)
#define CH 8             // src chunks (src>>14 -> 0..7); xw slice = 16384*192B = 3.1 MB < 4MB L2/XCD

// bf16 bits -> f32
DI float b2f(uint_t lo16) {
    union { uint_t u; float f; } v; v.u = lo16 << 16; return v.f;
}
// f32 -> bf16 bits, round-to-nearest-even
DI ushort_t f2b(float f) {
    union { float f; uint_t u; } v; v.f = f;
    uint_t u = v.u;
    uint_t r = (u + 0x7fffu + ((u >> 16) & 1u)) >> 16;
    return (ushort_t)r;
}

// fma 8 bf16 feats (packed in uint4) into acc[8]
DI void fma8(float* a, uint4 v, float nm) {
    a[0] += nm * b2f(v.x & 0xffffu); a[1] += nm * b2f(v.x >> 16);
    a[2] += nm * b2f(v.y & 0xffffu); a[3] += nm * b2f(v.y >> 16);
    a[4] += nm * b2f(v.z & 0xffffu); a[5] += nm * b2f(v.z >> 16);
    a[6] += nm * b2f(v.w & 0xffffu); a[7] += nm * b2f(v.w >> 16);
}

// ---------------- P1: bucket histogram (LDS-binned) --------------------------
__global__ __launch_bounds__(1024) void gcn_bhist(
    const int* __restrict__ ei, int* __restrict__ bkt_cnt, int E, int NB)
{
    __shared__ int hist[NBMAX];
    int t = threadIdx.x;
    for (int b = t; b < NB; b += 1024) hist[b] = 0;
    __syncthreads();
    int base = blockIdx.x * 32768;
    int lim = min(32768, E - base);
    for (int i = t; i < lim; i += 1024) {
        int d = ei[(size_t)E + base + i];
        atomicAdd(&hist[d >> 7], 1);
    }
    __syncthreads();
    for (int b = t; b < NB; b += 1024) {
        int c = hist[b];
        if (c) atomicAdd(&bkt_cnt[b], c);
    }
}

// ---------------- P2: scan bucket counts -> bases/cursors --------------------
__global__ __launch_bounds__(256) void gcn_bscan(
    const int* __restrict__ bkt_cnt, int* __restrict__ bkt_base,
    int* __restrict__ bkt_cursor, int NB, int E)
{
    __shared__ int lds[256];
    int t = threadIdx.x;
    int v[4]; int s = 0;
    #pragma unroll
    for (int j = 0; j < 4; j++) {
        int b = t * 4 + j;
        v[j] = (b < NB) ? bkt_cnt[b] : 0;
        s += v[j];
    }
    lds[t] = s;
    __syncthreads();
    #pragma unroll
    for (int off = 1; off < 256; off <<= 1) {
        int y = (t >= off) ? lds[t - off] : 0;
        __syncthreads();
        lds[t] += y;
        __syncthreads();
    }
    int run = lds[t] - s;
    #pragma unroll
    for (int j = 0; j < 4; j++) {
        int b = t * 4 + j;
        if (b < NB) { bkt_base[b] = run; bkt_cursor[b] = run; }
        run += v[j];
    }
    if (t == 255) bkt_base[NB] = E;
}

// ---------------- P3: scatter records into bucket regions --------------------
// record: x = src | (dst&127)<<17 ; y = |w| (f32 bits). Per-edge atomics are LDS.
__global__ __launch_bounds__(1024) void gcn_bscatter(
    const int* __restrict__ ei, const float* __restrict__ ew,
    int* __restrict__ bkt_cursor, uint2* __restrict__ stage, int E, int NB)
{
    __shared__ int hist[NBMAX];
    __shared__ int cur[NBMAX];
    int t = threadIdx.x;
    for (int b = t; b < NB; b += 1024) hist[b] = 0;
    __syncthreads();
    int base = blockIdx.x * 32768;
    int lim = min(32768, E - base);
    for (int i = t; i < lim; i += 1024) {
        int d = ei[(size_t)E + base + i];
        atomicAdd(&hist[d >> 7], 1);
    }
    __syncthreads();
    for (int b = t; b < NB; b += 1024) {
        int c = hist[b];
        cur[b] = c ? atomicAdd(&bkt_cursor[b], c) : 0;
    }
    __syncthreads();
    for (int i = t; i < lim; i += 1024) {
        int e = base + i;
        int s = ei[e];
        int d = ei[(size_t)E + e];
        float w = fabsf(ew[e]);
        int pos = atomicAdd(&cur[d >> 7], 1);
        uint2 rec;
        rec.x = (uint_t)s | ((uint_t)(d & 127) << 17);
        rec.y = __float_as_uint(w);
        stage[pos] = rec;
    }
}

// ---------------- P4: per-bucket counting sort by (node, src-chunk) ----------
// key = dst_local*CH + (src>>14). Emits rp8[(n)*8+ch] boundaries and dis.
__global__ __launch_bounds__(256) void gcn_bsort(
    const uint2* __restrict__ stage, uint2* __restrict__ edges,
    const int* __restrict__ bkt_base, int* __restrict__ rp8,
    float* __restrict__ dis, int N)
{
    int b = blockIdx.x;
    int base = bkt_base[b], end = bkt_base[b + 1];
    int cnte = end - base;
    int n0 = b << 7;
    __shared__ int cnt[NPB * CH];     // 1024 bins
    __shared__ float wsum[NPB];
    __shared__ int scn[256];
    __shared__ int cur[NPB * CH];
    int t = threadIdx.x;
    for (int i = t; i < NPB * CH; i += 256) cnt[i] = 0;
    if (t < NPB) wsum[t] = 0.0f;
    __syncthreads();
    for (int i = t; i < cnte; i += 256) {
        uint2 r = stage[base + i];
        int dl = (r.x >> 17) & 127;
        int ch = (r.x & 0x1FFFF) >> 14;
        atomicAdd(&cnt[dl * CH + ch], 1);
        atomicAdd(&wsum[dl], __uint_as_float(r.y));
    }
    __syncthreads();
    // scan the 1024 bins: thread t owns bins [4t, 4t+4)
    int v0 = cnt[t * 4], v1 = cnt[t * 4 + 1], v2 = cnt[t * 4 + 2], v3 = cnt[t * 4 + 3];
    int s = v0 + v1 + v2 + v3;
    scn[t] = s;
    __syncthreads();
    #pragma unroll
    for (int off = 1; off < 256; off <<= 1) {
        int y = (t >= off) ? scn[t - off] : 0;
        __syncthreads();
        scn[t] += y;
        __syncthreads();
    }
    int e0 = scn[t] - s;              // exclusive prefix of bin 4t
    int e1 = e0 + v0, e2 = e1 + v1, e3 = e2 + v2;
    cur[t * 4]     = base + e0;
    cur[t * 4 + 1] = base + e1;
    cur[t * 4 + 2] = base + e2;
    cur[t * 4 + 3] = base + e3;
    // rp8: absolute boundary per (node, chunk). Bins for nodes >= N are empty.
    size_t r8b = (size_t)n0 * 8 + t * 4;
    rp8[r8b]     = base + e0;
    rp8[r8b + 1] = base + e1;
    rp8[r8b + 2] = base + e2;
    rp8[r8b + 3] = base + e3;
    if ((t & 1) == 0) {
        int dl = t >> 1;
        int n = n0 + dl;
        if (n < N) dis[n] = rsqrtf(wsum[dl] + 1.0f);
    }
    __syncthreads();
    for (int i = t; i < cnte; i += 256) {
        uint2 r = stage[base + i];
        int dl = (r.x >> 17) & 127;
        int ch = (r.x & 0x1FFFF) >> 14;
        int pos = atomicAdd(&cur[dl * CH + ch], 1);
        edges[pos] = r;
    }
}

// ---------------- weight transpose + bf16 convert (once per call, tiny) -------
__global__ __launch_bounds__(256) void gcn_wt(
    const float* __restrict__ W1, const float* __restrict__ W2,
    const float* __restrict__ W3,
    ushort_t* __restrict__ Wt1, ushort_t* __restrict__ Wt2,
    ushort_t* __restrict__ Wt3)
{
    int i = blockIdx.x * 256 + threadIdx.x;
    if (i < 96 * 128) {                       // layer 1: Wt1[96][128]
        int n = i / 128, k = i % 128;
        Wt1[i] = f2b(W1[k * 96 + n]);
    }
    if (i < 96 * 96) {                        // layer 2: Wt2[96][96]
        int n = i / 96, k = i % 96;
        Wt2[i] = f2b(W2[k * 96 + n]);
    }
    if (i < 32 * 96) {                        // layer 3: Wt3[32][96], pad rows 30,31
        int n = i / 96, k = i % 96;
        Wt3[i] = f2b((n < 30) ? W3[k * 30 + n] : 0.0f);
    }
}

// ---------------- MFMA GEMM: Y[row,:] = dis[row] * (X[row,:] @ W) ------------
template<int K, int FOUT, int NTR, int FOUTP, bool XF32>
__global__ __launch_bounds__(256) void gcn_gemm_mfma(
    const void* __restrict__ Xv, const ushort_t* __restrict__ Wt,
    const float* __restrict__ dis, ushort_t* __restrict__ Y, int N)
{
    constexpr int KS = K + 8;
    constexpr int KT = K / 32;
    constexpr int NT = NTR / 16;
    __shared__ ushort_t xs[64 * KS];
    __shared__ ushort_t ws[NTR * KS];

    int t = threadIdx.x;
    int mbase = blockIdx.x * 64;

    {
        constexpr int TOT = NTR * (K / 8);
        const uint4* wg = (const uint4*)Wt;
        for (int i = t; i < TOT; i += 256) {
            int r = i / (K / 8), c8 = i % (K / 8);
            *(uint4*)(ws + r * KS + c8 * 8) = wg[i];
        }
    }
    if (XF32) {
        const float* X = (const float*)Xv;
        constexpr int TOT = 64 * (K / 4);
        for (int i = t; i < TOT; i += 256) {
            int row = i / (K / 4), c4 = i % (K / 4);
            int rg = mbase + row; if (rg >= N) rg = N - 1;
            float4 v = *(const float4*)(X + (size_t)rg * K + c4 * 4);
            uint2 pv;
            pv.x = (uint_t)f2b(v.x) | ((uint_t)f2b(v.y) << 16);
            pv.y = (uint_t)f2b(v.z) | ((uint_t)f2b(v.w) << 16);
            *(uint2*)(xs + row * KS + c4 * 4) = pv;
        }
    } else {
        const ushort_t* X = (const ushort_t*)Xv;
        constexpr int TOT = 64 * (K / 8);
        for (int i = t; i < TOT; i += 256) {
            int row = i / (K / 8), c8 = i % (K / 8);
            int rg = mbase + row; if (rg >= N) rg = N - 1;
            *(uint4*)(xs + row * KS + c8 * 8) = *(const uint4*)(X + (size_t)rg * K + c8 * 8);
        }
    }
    __syncthreads();

    int wave = t >> 6;
    int lane = t & 63;
    int l15 = lane & 15, quad = lane >> 4;

    bf16x8 af[KT];
    #pragma unroll
    for (int kt = 0; kt < KT; kt++)
        af[kt] = *(const bf16x8*)(xs + (wave * 16 + l15) * KS + kt * 32 + quad * 8);

    floatx4 acc[NT];
    #pragma unroll
    for (int nt = 0; nt < NT; nt++) acc[nt] = (floatx4){0.f, 0.f, 0.f, 0.f};

    #pragma unroll
    for (int nt = 0; nt < NT; nt++) {
        #pragma unroll
        for (int kt = 0; kt < KT; kt++) {
            bf16x8 bfr = *(const bf16x8*)(ws + (nt * 16 + l15) * KS + kt * 32 + quad * 8);
            acc[nt] = __builtin_amdgcn_mfma_f32_16x16x32_bf16(af[kt], bfr, acc[nt], 0, 0, 0);
        }
    }

    float dsc[4];
    #pragma unroll
    for (int r = 0; r < 4; r++) {
        int row = mbase + wave * 16 + quad * 4 + r;
        dsc[r] = (row < N) ? dis[row] : 0.0f;
    }
    #pragma unroll
    for (int nt = 0; nt < NT; nt++) {
        int col = nt * 16 + l15;
        #pragma unroll
        for (int r = 0; r < 4; r++) {
            int row = mbase + wave * 16 + quad * 4 + r;
            if (row < N) {
                float v = (col < FOUT) ? acc[nt][r] * dsc[r] : 0.0f;
                Y[(size_t)row * FOUTP + col] = f2b(v);
            }
        }
    }
}

// ---------------- aggregation: soft chunk-phased, register accumulators -------
// R6's gather structure (LPN lanes/node, reg acc, 4-wide MLP) + R7's chunk-major
// sweep, but NO barrier: all blocks co-resident (grid*waves < 8192) start
// chunk 0 together and progress statistically in phase -> shared ~3MB xw slice
// stays L2-resident without stalls.
// XWS = dis-scaled xw. H[n] = relu(b + dis[n]*(sum_e w*XWS[src] + XWS[n])).
template<int FOUT, int FOUTP, int LPN, int BLK, int S>
__global__ __launch_bounds__(BLK) void gcn_agg(
    const ushort_t* __restrict__ XWS, const int* __restrict__ rp8,
    const uint2* __restrict__ edges,
    const float* __restrict__ dis, const float* __restrict__ bias,
    ushort_t* __restrict__ H, int N)
{
    constexpr int NC = FOUTP / 8;           // uint4 per row
    constexpr int GPB = BLK / LPN;          // node groups per block
    int g = threadIdx.x / LPN;
    int c = threadIdx.x % LPN;
    int nb0 = blockIdx.x * (GPB * S);
    const uint4* xwc = (const uint4*)XWS;
    const u64_t* ed64 = (const u64_t*)edges;

    float a[S][8];
    int ebeg[S];
    #pragma unroll
    for (int s = 0; s < S; s++) {
        #pragma unroll
        for (int j = 0; j < 8; j++) a[s][j] = 0.0f;
        int n = nb0 + s * GPB + g;
        ebeg[s] = (n < N) ? rp8[(size_t)n * 8] : 0;
    }

    for (int ch = 0; ch < CH; ch++) {
        #pragma unroll
        for (int s = 0; s < S; s++) {
            int n = nb0 + s * GPB + g;
            if (n < N) {
                int eend = rp8[(size_t)n * 8 + ch + 1];
                int e = ebeg[s];
                for (; e + 4 <= eend; e += 4) {
                    u64_t r0 = __builtin_nontemporal_load(ed64 + e);
                    u64_t r1 = __builtin_nontemporal_load(ed64 + e + 1);
                    u64_t r2 = __builtin_nontemporal_load(ed64 + e + 2);
                    u64_t r3 = __builtin_nontemporal_load(ed64 + e + 3);
                    uint4 v0 = xwc[(size_t)((uint_t)r0 & 0x1FFFF) * NC + c];
                    uint4 v1 = xwc[(size_t)((uint_t)r1 & 0x1FFFF) * NC + c];
                    uint4 v2 = xwc[(size_t)((uint_t)r2 & 0x1FFFF) * NC + c];
                    uint4 v3 = xwc[(size_t)((uint_t)r3 & 0x1FFFF) * NC + c];
                    fma8(a[s], v0, __uint_as_float((uint_t)(r0 >> 32)));
                    fma8(a[s], v1, __uint_as_float((uint_t)(r1 >> 32)));
                    fma8(a[s], v2, __uint_as_float((uint_t)(r2 >> 32)));
                    fma8(a[s], v3, __uint_as_float((uint_t)(r3 >> 32)));
                }
                for (; e < eend; e++) {
                    u64_t r0 = __builtin_nontemporal_load(ed64 + e);
                    uint4 v0 = xwc[(size_t)((uint_t)r0 & 0x1FFFF) * NC + c];
                    fma8(a[s], v0, __uint_as_float((uint_t)(r0 >> 32)));
                }
                ebeg[s] = eend;
            }
        }
        // no __syncthreads(): soft phase coherence only
    }

    #pragma unroll
    for (int s = 0; s < S; s++) {
        int n = nb0 + s * GPB + g;
        if (n >= N) continue;
        uint4 sv = xwc[(size_t)n * NC + c];
        fma8(a[s], sv, 1.0f);                 // + XWS[n]
        float d = dis[n];
        int f0 = c * 8;
        uint_t o[4];
        #pragma unroll
        for (int p = 0; p < 4; p++) {
            float rA = (f0 + 2 * p     < FOUT) ? fmaxf(a[s][2 * p]     * d + bias[f0 + 2 * p],     0.f) : 0.f;
            float rB = (f0 + 2 * p + 1 < FOUT) ? fmaxf(a[s][2 * p + 1] * d + bias[f0 + 2 * p + 1], 0.f) : 0.f;
            o[p] = (uint_t)f2b(rA) | ((uint_t)f2b(rB) << 16);
        }
        uint4 ov = {o[0], o[1], o[2], o[3]};
        *((uint4*)H + (size_t)n * NC + c) = ov;
    }
}

// ---------------- mean-pool per graph + final linear + softmax ----------------
__global__ __launch_bounds__(256) void gcn_pool(
    const ushort_t* __restrict__ H, const int* __restrict__ batch,
    const float* __restrict__ Wf, const float* __restrict__ bf_,
    float* __restrict__ out, int N)
{
    __shared__ float pool[32];
    int g = blockIdx.x;
    int t = threadIdx.x;

    int lo = 0, hi = N;
    while (lo < hi) { int mid = (lo + hi) >> 1; if (batch[mid] < g) lo = mid + 1; else hi = mid; }
    int start = lo;
    lo = 0; hi = N;
    while (lo < hi) { int mid = (lo + hi) >> 1; if (batch[mid] < g + 1) lo = mid + 1; else hi = mid; }
    int end = lo;

    float acc[32];
    #pragma unroll
    for (int f = 0; f < 32; f++) acc[f] = 0.0f;
    for (int i = start + t; i < end; i += 256) {
        const uint2* hr = (const uint2*)H + (size_t)i * 8;
        #pragma unroll
        for (int q = 0; q < 8; q++) {
            uint2 v = hr[q];
            acc[4 * q + 0] += b2f(v.x & 0xffffu);
            acc[4 * q + 1] += b2f(v.x >> 16);
            acc[4 * q + 2] += b2f(v.y & 0xffffu);
            acc[4 * q + 3] += b2f(v.y >> 16);
        }
    }
    #pragma unroll
    for (int f = 0; f < 32; f++) {
        float v = acc[f];
        v += __shfl_down(v, 32, 64);
        v += __shfl_down(v, 16, 64);
        v += __shfl_down(v, 8, 64);
        v += __shfl_down(v, 4, 64);
        v += __shfl_down(v, 2, 64);
        v += __shfl_down(v, 1, 64);
        acc[f] = v;
    }
    if (t < 32) pool[t] = 0.0f;
    __syncthreads();
    if ((t & 63) == 0) {
        #pragma unroll
        for (int f = 0; f < 30; f++) atomicAdd(&pool[f], acc[f]);
    }
    __syncthreads();
    if (t == 0) {
        float inv = 1.0f / fmaxf((float)(end - start), 1.0f);
        float lg[10];
        #pragma unroll
        for (int j = 0; j < 10; j++) lg[j] = bf_[j];
        for (int f = 0; f < 30; f++) {
            float p = pool[f] * inv;
            #pragma unroll
            for (int j = 0; j < 10; j++) lg[j] += p * Wf[f * 10 + j];
        }
        float m = lg[0];
        #pragma unroll
        for (int j = 1; j < 10; j++) m = fmaxf(m, lg[j]);
        float s = 0.f;
        #pragma unroll
        for (int j = 0; j < 10; j++) { lg[j] = __expf(lg[j] - m); s += lg[j]; }
        float is = 1.0f / s;
        #pragma unroll
        for (int j = 0; j < 10; j++) out[g * 10 + j] = lg[j] * is;
    }
}

extern "C" void kernel_launch(void* const* d_in, const int* in_sizes, int n_in,
                              void* d_out, int out_size, void* d_ws, size_t ws_size,
                              hipStream_t stream) {
    (void)n_in; (void)out_size; (void)ws_size;
    const float* x   = (const float*)d_in[0];
    const int*   ei  = (const int*)d_in[1];
    const float* ew  = (const float*)d_in[2];
    const int*   bat = (const int*)d_in[3];
    const float* W1  = (const float*)d_in[4];
    const float* b1  = (const float*)d_in[5];
    const float* W2  = (const float*)d_in[6];
    const float* b2  = (const float*)d_in[7];
    const float* W3  = (const float*)d_in[8];
    const float* b3  = (const float*)d_in[9];
    const float* Wf  = (const float*)d_in[10];
    const float* bf_ = (const float*)d_in[11];
    float* out = (float*)d_out;

    const int N = in_sizes[3];       // 100000
    const int E = in_sizes[2];       // 3200000
    const int NB = (N + NPB - 1) / NPB;   // 782

    char* wsb = (char*)d_ws;
    size_t o = 0;
    auto take = [&](size_t bytes) -> char* {
        char* p = wsb + o;
        o += (bytes + 255) & ~(size_t)255;
        return p;
    };
    int*      bkt_cnt    = (int*)take(NBMAX * 4);             // zeroed each call
    int*      bkt_base   = (int*)take((NBMAX + 1) * 4);
    int*      bkt_cursor = (int*)take(NBMAX * 4);
    int*      rp8        = (int*)take(((size_t)NB * NPB * 8 + 16) * 4);
    float*    dis        = (float*)take((size_t)N * 4);
    uint2*    stage      = (uint2*)take((size_t)E * 8);       // dead after bsort; xw aliases it
    uint2*    edges      = (uint2*)take((size_t)E * 8);
    ushort_t* h          = (ushort_t*)take((size_t)N * 96 * 2);
    ushort_t* Wt1        = (ushort_t*)take(96 * 128 * 2);
    ushort_t* Wt2        = (ushort_t*)take(96 * 96 * 2);
    ushort_t* Wt3        = (ushort_t*)take(32 * 96 * 2);
    ushort_t* xw         = (ushort_t*)stage;                  // alias (E*8 >= N*96*2)

    const int gB = (E + 32767) / 32768;       // 98
    const int gM = (N + 63) / 64;

    hipMemsetAsync(bkt_cnt, 0, NBMAX * 4, stream);

    // CSR build: bucket hist -> scan -> scatter -> per-bucket sort (emits rp8, dis)
    gcn_bhist<<<gB, 1024, 0, stream>>>(ei, bkt_cnt, E, NB);
    gcn_wt<<<48, 256, 0, stream>>>(W1, W2, W3, Wt1, Wt2, Wt3);
    gcn_bscan<<<1, 256, 0, stream>>>(bkt_cnt, bkt_base, bkt_cursor, NB, E);
    gcn_bscatter<<<gB, 1024, 0, stream>>>(ei, ew, bkt_cursor, stage, E, NB);
    gcn_bsort<<<NB, 256, 0, stream>>>(stage, edges, bkt_base, rp8, dis, N);

    // agg grids: block owns GPB*S nodes; all blocks co-resident
    const int gA96 = (N + 16 * 4 - 1) / (16 * 4);    // 1563 blocks x 3 waves
    const int gA32 = (N + 64 * 4 - 1) / (64 * 4);    // 391 blocks x 4 waves

    // layer 1: x[.,128](fp32) -> xws[.,96](bf16, dis-scaled) -> h[.,96](bf16)
    gcn_gemm_mfma<128, 96, 96, 96, true><<<gM, 256, 0, stream>>>(x, Wt1, dis, xw, N);
    gcn_agg<96, 96, 12, 192, 4><<<gA96, 192, 0, stream>>>(xw, rp8, edges, dis, b1, h, N);

    // layer 2
    gcn_gemm_mfma<96, 96, 96, 96, false><<<gM, 256, 0, stream>>>(h, Wt2, dis, xw, N);
    gcn_agg<96, 96, 12, 192, 4><<<gA96, 192, 0, stream>>>(xw, rp8, edges, dis, b2, h, N);

    // layer 3 (FOUT=30 padded to 32)
    gcn_gemm_mfma<96, 30, 32, 32, false><<<gM, 256, 0, stream>>>(h, Wt3, dis, xw, N);
    gcn_agg<30, 32, 4, 256, 4><<<gA32, 256, 0, stream>>>(xw, rp8, edges, dis, b3, h, N);

    // mean pool + classifier + softmax
    gcn_pool<<<256, 256, 0, stream>>>(h, bat, Wf, bf_, out, N);
}

// Round 10
// 869.271 us; speedup vs baseline: 5.0925x; 1.0348x over previous
//
#include <hip/hip_runtime.h>
#include <hip/hip_bf16.h>

typedef unsigned short ushort_t;
typedef unsigned int uint_t;
typedef unsigned long long u64_t;

typedef __attribute__((ext_vector_type(8))) short bf16x8;   // 8 bf16 (4 VGPRs)
typedef __attribute__((ext_vector_type(4))) float floatx4;  // MFMA C/D

#define DI __device__ __forceinline__

// NOTE: record packing uses 17 bits for src -> requires N < 131072. (N=100000)
#define NPB 128          // nodes per bucket
#define NBMAX 1024       // max buckets (N <= 131072)
#define CH 8             // src chunks (src>>14 -> 0..7); xw slice = 16384*192B = 3.1 MB < 4MB L2/XCD

// bf16 bits -> f32
DI float b2f(uint_t lo16) {
    union { uint_t u; float f; } v; v.u = lo16 << 16; return v.f;
}
// f32 -> bf16 bits, round-to-nearest-even
DI ushort_t f2b(float f) {
    union { float f; uint_t u; } v; v.f = f;
    uint_t u = v.u;
    uint_t r = (u + 0x7fffu + ((u >> 16) & 1u)) >> 16;
    return (ushort_t)r;
}

// fma 8 bf16 feats (packed in uint4) into acc[8]
DI void fma8(float* a, uint4 v, float nm) {
    a[0] += nm * b2f(v.x & 0xffffu); a[1] += nm * b2f(v.x >> 16);
    a[2] += nm * b2f(v.y & 0xffffu); a[3] += nm * b2f(v.y >> 16);
    a[4] += nm * b2f(v.z & 0xffffu); a[5] += nm * b2f(v.z >> 16);
    a[6] += nm * b2f(v.w & 0xffffu); a[7] += nm * b2f(v.w >> 16);
}

// ---------------- P1: bucket histogram (LDS-binned) --------------------------
// Also persists this block's per-bucket counts row to hist_g (for deterministic
// scatter placement -- removes bscatter's histogram pre-pass).
__global__ __launch_bounds__(1024) void gcn_bhist(
    const int* __restrict__ ei, int* __restrict__ bkt_cnt,
    int* __restrict__ hist_g, int E, int NB)
{
    __shared__ int hist[NBMAX];
    int t = threadIdx.x;
    for (int b = t; b < NB; b += 1024) hist[b] = 0;
    __syncthreads();
    int base = blockIdx.x * 32768;
    int lim = min(32768, E - base);
    for (int i = t; i < lim; i += 1024) {
        int d = ei[(size_t)E + base + i];
        atomicAdd(&hist[d >> 7], 1);
    }
    __syncthreads();
    int* row = hist_g + (size_t)blockIdx.x * NBMAX;
    for (int b = t; b < NB; b += 1024) {
        int c = hist[b];
        row[b] = c;
        if (c) atomicAdd(&bkt_cnt[b], c);
    }
}

// ---------------- P2: scan bucket counts -> bases ----------------------------
__global__ __launch_bounds__(256) void gcn_bscan(
    const int* __restrict__ bkt_cnt, int* __restrict__ bkt_base, int NB, int E)
{
    __shared__ int lds[256];
    int t = threadIdx.x;
    int v[4]; int s = 0;
    #pragma unroll
    for (int j = 0; j < 4; j++) {
        int b = t * 4 + j;
        v[j] = (b < NB) ? bkt_cnt[b] : 0;
        s += v[j];
    }
    lds[t] = s;
    __syncthreads();
    #pragma unroll
    for (int off = 1; off < 256; off <<= 1) {
        int y = (t >= off) ? lds[t - off] : 0;
        __syncthreads();
        lds[t] += y;
        __syncthreads();
    }
    int run = lds[t] - s;
    #pragma unroll
    for (int j = 0; j < 4; j++) {
        int b = t * 4 + j;
        if (b < NB) bkt_base[b] = run;
        run += v[j];
    }
    if (t == 255) bkt_base[NB] = E;
}

// ---------------- P2b: rebase per-block rows -> deterministic write bases ----
// hist_g[r][k] := bkt_base[k] + sum_{r'<r} hist_g[r'][k]
__global__ __launch_bounds__(256) void gcn_brebase(
    int* __restrict__ hist_g, const int* __restrict__ bkt_base, int NB, int nrows)
{
    int k = blockIdx.x * 256 + threadIdx.x;
    if (k >= NB) return;
    int run = bkt_base[k];
    for (int r = 0; r < nrows; r++) {
        int* p = hist_g + (size_t)r * NBMAX + k;
        int v = *p;
        *p = run;
        run += v;
    }
}

// ---------------- P3: scatter records into bucket regions (no atomics on glb) -
// record: x = src | (dst&127)<<17 ; y = |w| (f32 bits). Per-edge atomics are LDS.
__global__ __launch_bounds__(1024) void gcn_bscatter(
    const int* __restrict__ ei, const float* __restrict__ ew,
    const int* __restrict__ hist_g, uint2* __restrict__ stage, int E, int NB)
{
    __shared__ int cur[NBMAX];
    int t = threadIdx.x;
    const int* row = hist_g + (size_t)blockIdx.x * NBMAX;
    for (int b = t; b < NB; b += 1024) cur[b] = row[b];
    __syncthreads();
    int base = blockIdx.x * 32768;
    int lim = min(32768, E - base);
    for (int i = t; i < lim; i += 1024) {
        int e = base + i;
        int s = ei[e];
        int d = ei[(size_t)E + e];
        float w = fabsf(ew[e]);
        int pos = atomicAdd(&cur[d >> 7], 1);
        uint2 rec;
        rec.x = (uint_t)s | ((uint_t)(d & 127) << 17);
        rec.y = __float_as_uint(w);
        stage[pos] = rec;
    }
}

// ---------------- P4: per-bucket counting sort by (node, src-chunk) ----------
// key = dst_local*CH + (src>>14). Emits rp8[(n)*8+ch] boundaries and dis.
__global__ __launch_bounds__(256) void gcn_bsort(
    const uint2* __restrict__ stage, uint2* __restrict__ edges,
    const int* __restrict__ bkt_base, int* __restrict__ rp8,
    float* __restrict__ dis, int N)
{
    int b = blockIdx.x;
    int base = bkt_base[b], end = bkt_base[b + 1];
    int cnte = end - base;
    int n0 = b << 7;
    __shared__ int cnt[NPB * CH];     // 1024 bins
    __shared__ float wsum[NPB];
    __shared__ int scn[256];
    __shared__ int cur[NPB * CH];
    int t = threadIdx.x;
    for (int i = t; i < NPB * CH; i += 256) cnt[i] = 0;
    if (t < NPB) wsum[t] = 0.0f;
    __syncthreads();
    for (int i = t; i < cnte; i += 256) {
        uint2 r = stage[base + i];
        int dl = (r.x >> 17) & 127;
        int ch = (r.x & 0x1FFFF) >> 14;
        atomicAdd(&cnt[dl * CH + ch], 1);
        atomicAdd(&wsum[dl], __uint_as_float(r.y));
    }
    __syncthreads();
    // scan the 1024 bins: thread t owns bins [4t, 4t+4)
    int v0 = cnt[t * 4], v1 = cnt[t * 4 + 1], v2 = cnt[t * 4 + 2], v3 = cnt[t * 4 + 3];
    int s = v0 + v1 + v2 + v3;
    scn[t] = s;
    __syncthreads();
    #pragma unroll
    for (int off = 1; off < 256; off <<= 1) {
        int y = (t >= off) ? scn[t - off] : 0;
        __syncthreads();
        scn[t] += y;
        __syncthreads();
    }
    int e0 = scn[t] - s;              // exclusive prefix of bin 4t
    int e1 = e0 + v0, e2 = e1 + v1, e3 = e2 + v2;
    cur[t * 4]     = base + e0;
    cur[t * 4 + 1] = base + e1;
    cur[t * 4 + 2] = base + e2;
    cur[t * 4 + 3] = base + e3;
    // rp8: absolute boundary per (node, chunk). Bins for nodes >= N are empty.
    size_t r8b = (size_t)n0 * 8 + t * 4;
    rp8[r8b]     = base + e0;
    rp8[r8b + 1] = base + e1;
    rp8[r8b + 2] = base + e2;
    rp8[r8b + 3] = base + e3;
    if ((t & 1) == 0) {
        int dl = t >> 1;
        int n = n0 + dl;
        if (n < N) dis[n] = rsqrtf(wsum[dl] + 1.0f);
    }
    __syncthreads();
    for (int i = t; i < cnte; i += 256) {
        uint2 r = stage[base + i];
        int dl = (r.x >> 17) & 127;
        int ch = (r.x & 0x1FFFF) >> 14;
        int pos = atomicAdd(&cur[dl * CH + ch], 1);
        edges[pos] = r;
    }
}

// ---------------- weight transpose + bf16 convert (once per call, tiny) -------
__global__ __launch_bounds__(256) void gcn_wt(
    const float* __restrict__ W1, const float* __restrict__ W2,
    const float* __restrict__ W3,
    ushort_t* __restrict__ Wt1, ushort_t* __restrict__ Wt2,
    ushort_t* __restrict__ Wt3)
{
    int i = blockIdx.x * 256 + threadIdx.x;
    if (i < 96 * 128) {                       // layer 1: Wt1[96][128]
        int n = i / 128, k = i % 128;
        Wt1[i] = f2b(W1[k * 96 + n]);
    }
    if (i < 96 * 96) {                        // layer 2: Wt2[96][96]
        int n = i / 96, k = i % 96;
        Wt2[i] = f2b(W2[k * 96 + n]);
    }
    if (i < 32 * 96) {                        // layer 3: Wt3[32][96], pad rows 30,31
        int n = i / 96, k = i % 96;
        Wt3[i] = f2b((n < 30) ? W3[k * 30 + n] : 0.0f);
    }
}

// ---------------- MFMA GEMM: Y[row,:] = dis[row] * (X[row,:] @ W) ------------
template<int K, int FOUT, int NTR, int FOUTP, bool XF32>
__global__ __launch_bounds__(256) void gcn_gemm_mfma(
    const void* __restrict__ Xv, const ushort_t* __restrict__ Wt,
    const float* __restrict__ dis, ushort_t* __restrict__ Y, int N)
{
    constexpr int KS = K + 8;
    constexpr int KT = K / 32;
    constexpr int NT = NTR / 16;
    __shared__ ushort_t xs[64 * KS];
    __shared__ ushort_t ws[NTR * KS];

    int t = threadIdx.x;
    int mbase = blockIdx.x * 64;

    {
        constexpr int TOT = NTR * (K / 8);
        const uint4* wg = (const uint4*)Wt;
        for (int i = t; i < TOT; i += 256) {
            int r = i / (K / 8), c8 = i % (K / 8);
            *(uint4*)(ws + r * KS + c8 * 8) = wg[i];
        }
    }
    if (XF32) {
        const float* X = (const float*)Xv;
        constexpr int TOT = 64 * (K / 4);
        for (int i = t; i < TOT; i += 256) {
            int row = i / (K / 4), c4 = i % (K / 4);
            int rg = mbase + row; if (rg >= N) rg = N - 1;
            float4 v = *(const float4*)(X + (size_t)rg * K + c4 * 4);
            uint2 pv;
            pv.x = (uint_t)f2b(v.x) | ((uint_t)f2b(v.y) << 16);
            pv.y = (uint_t)f2b(v.z) | ((uint_t)f2b(v.w) << 16);
            *(uint2*)(xs + row * KS + c4 * 4) = pv;
        }
    } else {
        const ushort_t* X = (const ushort_t*)Xv;
        constexpr int TOT = 64 * (K / 8);
        for (int i = t; i < TOT; i += 256) {
            int row = i / (K / 8), c8 = i % (K / 8);
            int rg = mbase + row; if (rg >= N) rg = N - 1;
            *(uint4*)(xs + row * KS + c8 * 8) = *(const uint4*)(X + (size_t)rg * K + c8 * 8);
        }
    }
    __syncthreads();

    int wave = t >> 6;
    int lane = t & 63;
    int l15 = lane & 15, quad = lane >> 4;

    bf16x8 af[KT];
    #pragma unroll
    for (int kt = 0; kt < KT; kt++)
        af[kt] = *(const bf16x8*)(xs + (wave * 16 + l15) * KS + kt * 32 + quad * 8);

    floatx4 acc[NT];
    #pragma unroll
    for (int nt = 0; nt < NT; nt++) acc[nt] = (floatx4){0.f, 0.f, 0.f, 0.f};

    #pragma unroll
    for (int nt = 0; nt < NT; nt++) {
        #pragma unroll
        for (int kt = 0; kt < KT; kt++) {
            bf16x8 bfr = *(const bf16x8*)(ws + (nt * 16 + l15) * KS + kt * 32 + quad * 8);
            acc[nt] = __builtin_amdgcn_mfma_f32_16x16x32_bf16(af[kt], bfr, acc[nt], 0, 0, 0);
        }
    }

    float dsc[4];
    #pragma unroll
    for (int r = 0; r < 4; r++) {
        int row = mbase + wave * 16 + quad * 4 + r;
        dsc[r] = (row < N) ? dis[row] : 0.0f;
    }
    #pragma unroll
    for (int nt = 0; nt < NT; nt++) {
        int col = nt * 16 + l15;
        #pragma unroll
        for (int r = 0; r < 4; r++) {
            int row = mbase + wave * 16 + quad * 4 + r;
            if (row < N) {
                float v = (col < FOUT) ? acc[nt][r] * dsc[r] : 0.0f;
                Y[(size_t)row * FOUTP + col] = f2b(v);
            }
        }
    }
}

// ---------------- aggregation: soft chunk-phased, boundaries prefetched -------
// All chunk boundaries per node loaded ONCE up front (2x uint4 + 1 scalar,
// packed as u16 deltas in 4 regs/node) -> chunk loop has no dependent index
// loads. Grid all-resident (no oversubscription) so co-residency keeps gathers
// phase-coherent over a ~3MB xw slice per chunk (R9: FETCH at the 190MB floor).
// XWS = dis-scaled xw. H[n] = relu(b + dis[n]*(sum_e w*XWS[src] + XWS[n])).
template<int FOUT, int FOUTP, int LPN, int BLK, int S>
__global__ __launch_bounds__(BLK) void gcn_agg(
    const ushort_t* __restrict__ XWS, const int* __restrict__ rp8,
    const uint2* __restrict__ edges,
    const float* __restrict__ dis, const float* __restrict__ bias,
    ushort_t* __restrict__ H, int N)
{
    constexpr int NC = FOUTP / 8;           // uint4 per row
    constexpr int GPB = BLK / LPN;          // node groups per block
    int g = threadIdx.x / LPN;
    int c = threadIdx.x % LPN;
    int nb0 = blockIdx.x * (GPB * S);
    const uint4* xwc = (const uint4*)XWS;
    const u64_t* ed64 = (const u64_t*)edges;

    float a[S][8];
    int st[S];            // segment start (absolute) = rp8[n*8]
    int ec[S];            // running edge cursor
    uint_t pk[S][4];      // packed u16 deltas of chunk ends (ch0..7)
    #pragma unroll
    for (int s = 0; s < S; s++) {
        #pragma unroll
        for (int j = 0; j < 8; j++) a[s][j] = 0.0f;
        int n = nb0 + s * GPB + g;
        bool ok = (n < N);
        int nn = ok ? n : N - 1;
        const int* rb = rp8 + (size_t)nn * 8;
        uint4 lo = *(const uint4*)rb;        // st, e0, e1, e2
        uint4 hi = *(const uint4*)(rb + 4);  // e3, e4, e5, e6
        int e7 = rb[8];
        int s0 = (int)lo.x;
        st[s] = s0; ec[s] = s0;
        if (ok) {
            pk[s][0] = ((lo.z - s0) << 16) | (uint_t)(lo.y - s0);
            pk[s][1] = ((hi.x - s0) << 16) | (uint_t)(lo.w - s0);
            pk[s][2] = ((hi.z - s0) << 16) | (uint_t)(hi.y - s0);
            pk[s][3] = (((uint_t)(e7 - s0)) << 16) | (uint_t)(hi.w - s0);
        } else {
            pk[s][0] = pk[s][1] = pk[s][2] = pk[s][3] = 0;
        }
    }

    #pragma unroll
    for (int ch = 0; ch < CH; ch++) {
        #pragma unroll
        for (int s = 0; s < S; s++) {
            int eend = st[s] + (int)((pk[s][ch >> 1] >> ((ch & 1) * 16)) & 0xFFFFu);
            int e = ec[s];
            for (; e + 4 <= eend; e += 4) {
                u64_t r0 = __builtin_nontemporal_load(ed64 + e);
                u64_t r1 = __builtin_nontemporal_load(ed64 + e + 1);
                u64_t r2 = __builtin_nontemporal_load(ed64 + e + 2);
                u64_t r3 = __builtin_nontemporal_load(ed64 + e + 3);
                uint4 v0 = xwc[(size_t)((uint_t)r0 & 0x1FFFF) * NC + c];
                uint4 v1 = xwc[(size_t)((uint_t)r1 & 0x1FFFF) * NC + c];
                uint4 v2 = xwc[(size_t)((uint_t)r2 & 0x1FFFF) * NC + c];
                uint4 v3 = xwc[(size_t)((uint_t)r3 & 0x1FFFF) * NC + c];
                fma8(a[s], v0, __uint_as_float((uint_t)(r0 >> 32)));
                fma8(a[s], v1, __uint_as_float((uint_t)(r1 >> 32)));
                fma8(a[s], v2, __uint_as_float((uint_t)(r2 >> 32)));
                fma8(a[s], v3, __uint_as_float((uint_t)(r3 >> 32)));
            }
            for (; e < eend; e++) {
                u64_t r0 = __builtin_nontemporal_load(ed64 + e);
                uint4 v0 = xwc[(size_t)((uint_t)r0 & 0x1FFFF) * NC + c];
                fma8(a[s], v0, __uint_as_float((uint_t)(r0 >> 32)));
            }
            ec[s] = e;
        }
        // no barrier: soft phase coherence via co-residency
    }

    #pragma unroll
    for (int s = 0; s < S; s++) {
        int n = nb0 + s * GPB + g;
        if (n >= N) continue;
        uint4 sv = xwc[(size_t)n * NC + c];
        fma8(a[s], sv, 1.0f);                 // + XWS[n]
        float d = dis[n];
        int f0 = c * 8;
        uint_t o[4];
        #pragma unroll
        for (int p = 0; p < 4; p++) {
            float rA = (f0 + 2 * p     < FOUT) ? fmaxf(a[s][2 * p]     * d + bias[f0 + 2 * p],     0.f) : 0.f;
            float rB = (f0 + 2 * p + 1 < FOUT) ? fmaxf(a[s][2 * p + 1] * d + bias[f0 + 2 * p + 1], 0.f) : 0.f;
            o[p] = (uint_t)f2b(rA) | ((uint_t)f2b(rB) << 16);
        }
        uint4 ov = {o[0], o[1], o[2], o[3]};
        *((uint4*)H + (size_t)n * NC + c) = ov;
    }
}

// ---------------- mean-pool per graph + final linear + softmax ----------------
__global__ __launch_bounds__(256) void gcn_pool(
    const ushort_t* __restrict__ H, const int* __restrict__ batch,
    const float* __restrict__ Wf, const float* __restrict__ bf_,
    float* __restrict__ out, int N)
{
    __shared__ float pool[32];
    int g = blockIdx.x;
    int t = threadIdx.x;

    int lo = 0, hi = N;
    while (lo < hi) { int mid = (lo + hi) >> 1; if (batch[mid] < g) lo = mid + 1; else hi = mid; }
    int start = lo;
    lo = 0; hi = N;
    while (lo < hi) { int mid = (lo + hi) >> 1; if (batch[mid] < g + 1) lo = mid + 1; else hi = mid; }
    int end = lo;

    float acc[32];
    #pragma unroll
    for (int f = 0; f < 32; f++) acc[f] = 0.0f;
    for (int i = start + t; i < end; i += 256) {
        const uint2* hr = (const uint2*)H + (size_t)i * 8;
        #pragma unroll
        for (int q = 0; q < 8; q++) {
            uint2 v = hr[q];
            acc[4 * q + 0] += b2f(v.x & 0xffffu);
            acc[4 * q + 1] += b2f(v.x >> 16);
            acc[4 * q + 2] += b2f(v.y & 0xffffu);
            acc[4 * q + 3] += b2f(v.y >> 16);
        }
    }
    #pragma unroll
    for (int f = 0; f < 32; f++) {
        float v = acc[f];
        v += __shfl_down(v, 32, 64);
        v += __shfl_down(v, 16, 64);
        v += __shfl_down(v, 8, 64);
        v += __shfl_down(v, 4, 64);
        v += __shfl_down(v, 2, 64);
        v += __shfl_down(v, 1, 64);
        acc[f] = v;
    }
    if (t < 32) pool[t] = 0.0f;
    __syncthreads();
    if ((t & 63) == 0) {
        #pragma unroll
        for (int f = 0; f < 30; f++) atomicAdd(&pool[f], acc[f]);
    }
    __syncthreads();
    if (t == 0) {
        float inv = 1.0f / fmaxf((float)(end - start), 1.0f);
        float lg[10];
        #pragma unroll
        for (int j = 0; j < 10; j++) lg[j] = bf_[j];
        for (int f = 0; f < 30; f++) {
            float p = pool[f] * inv;
            #pragma unroll
            for (int j = 0; j < 10; j++) lg[j] += p * Wf[f * 10 + j];
        }
        float m = lg[0];
        #pragma unroll
        for (int j = 1; j < 10; j++) m = fmaxf(m, lg[j]);
        float s = 0.f;
        #pragma unroll
        for (int j = 0; j < 10; j++) { lg[j] = __expf(lg[j] - m); s += lg[j]; }
        float is = 1.0f / s;
        #pragma unroll
        for (int j = 0; j < 10; j++) out[g * 10 + j] = lg[j] * is;
    }
}

extern "C" void kernel_launch(void* const* d_in, const int* in_sizes, int n_in,
                              void* d_out, int out_size, void* d_ws, size_t ws_size,
                              hipStream_t stream) {
    (void)n_in; (void)out_size; (void)ws_size;
    const float* x   = (const float*)d_in[0];
    const int*   ei  = (const int*)d_in[1];
    const float* ew  = (const float*)d_in[2];
    const int*   bat = (const int*)d_in[3];
    const float* W1  = (const float*)d_in[4];
    const float* b1  = (const float*)d_in[5];
    const float* W2  = (const float*)d_in[6];
    const float* b2  = (const float*)d_in[7];
    const float* W3  = (const float*)d_in[8];
    const float* b3  = (const float*)d_in[9];
    const float* Wf  = (const float*)d_in[10];
    const float* bf_ = (const float*)d_in[11];
    float* out = (float*)d_out;

    const int N = in_sizes[3];       // 100000
    const int E = in_sizes[2];       // 3200000
    const int NB = (N + NPB - 1) / NPB;   // 782
    const int gB = (E + 32767) / 32768;   // 98

    char* wsb = (char*)d_ws;
    size_t o = 0;
    auto take = [&](size_t bytes) -> char* {
        char* p = wsb + o;
        o += (bytes + 255) & ~(size_t)255;
        return p;
    };
    int*      bkt_cnt    = (int*)take(NBMAX * 4);             // zeroed each call
    int*      bkt_base   = (int*)take((NBMAX + 1) * 4);
    int*      hist_g     = (int*)take((size_t)gB * NBMAX * 4);
    int*      rp8        = (int*)take(((size_t)NB * NPB * 8 + 16) * 4);
    float*    dis        = (float*)take((size_t)N * 4);
    uint2*    stage      = (uint2*)take((size_t)E * 8);       // dead after bsort; xw aliases it
    uint2*    edges      = (uint2*)take((size_t)E * 8);
    ushort_t* h          = (ushort_t*)take((size_t)N * 96 * 2);
    ushort_t* Wt1        = (ushort_t*)take(96 * 128 * 2);
    ushort_t* Wt2        = (ushort_t*)take(96 * 96 * 2);
    ushort_t* Wt3        = (ushort_t*)take(32 * 96 * 2);
    ushort_t* xw         = (ushort_t*)stage;                  // alias (E*8 >= N*96*2)

    const int gM = (N + 63) / 64;

    hipMemsetAsync(bkt_cnt, 0, NBMAX * 4, stream);

    // CSR build: hist (+rows) -> scan -> rebase -> deterministic scatter -> sort
    gcn_bhist<<<gB, 1024, 0, stream>>>(ei, bkt_cnt, hist_g, E, NB);
    gcn_wt<<<48, 256, 0, stream>>>(W1, W2, W3, Wt1, Wt2, Wt3);
    gcn_bscan<<<1, 256, 0, stream>>>(bkt_cnt, bkt_base, NB, E);
    gcn_brebase<<<(NB + 255) / 256, 256, 0, stream>>>(hist_g, bkt_base, NB, gB);
    gcn_bscatter<<<gB, 1024, 0, stream>>>(ei, ew, hist_g, stage, E, NB);
    gcn_bsort<<<NB, 256, 0, stream>>>(stage, edges, bkt_base, rp8, dis, N);

    // agg grids: block owns GPB*S nodes; all blocks co-resident (no oversub)
    const int gA96 = (N + 16 * 4 - 1) / (16 * 4);    // 1563 blocks x 3 waves
    const int gA32 = (N + 64 * 4 - 1) / (64 * 4);    // 391 blocks x 4 waves

    // layer 1: x[.,128](fp32) -> xws[.,96](bf16, dis-scaled) -> h[.,96](bf16)
    gcn_gemm_mfma<128, 96, 96, 96, true><<<gM, 256, 0, stream>>>(x, Wt1, dis, xw, N);
    gcn_agg<96, 96, 12, 192, 4><<<gA96, 192, 0, stream>>>(xw, rp8, edges, dis, b1, h, N);

    // layer 2
    gcn_gemm_mfma<96, 96, 96, 96, false><<<gM, 256, 0, stream>>>(h, Wt2, dis, xw, N);
    gcn_agg<96, 96, 12, 192, 4><<<gA96, 192, 0, stream>>>(xw, rp8, edges, dis, b2, h, N);

    // layer 3 (FOUT=30 padded to 32)
    gcn_gemm_mfma<96, 30, 32, 32, false><<<gM, 256, 0, stream>>>(h, Wt3, dis, xw, N);
    gcn_agg<30, 32, 4, 256, 4><<<gA32, 256, 0, stream>>>(xw, rp8, edges, dis, b3, h, N);

    // mean pool + classifier + softmax
    gcn_pool<<<256, 256, 0, stream>>>(h, bat, Wf, bf_, out, N);
}

// Round 11
// 627.790 us; speedup vs baseline: 7.0513x; 1.3847x over previous
//
#include <hip/hip_runtime.h>
#include <hip/hip_bf16.h>

typedef unsigned short ushort_t;
typedef unsigned int uint_t;
typedef unsigned long long u64_t;

typedef __attribute__((ext_vector_type(8))) short bf16x8;   // 8 bf16 (4 VGPRs)
typedef __attribute__((ext_vector_type(4))) float floatx4;  // MFMA C/D

#define DI __device__ __forceinline__

// NOTE: record packing uses 17 bits for src -> requires N < 131072. (N=100000)
#define NPB 128          // nodes per bucket
#define NBMAX 1024       // max buckets (N <= 131072)
#define CH 8             // src chunks (kept in sort key; harmless ordering)

// bf16 bits -> f32
DI float b2f(uint_t lo16) {
    union { uint_t u; float f; } v; v.u = lo16 << 16; return v.f;
}
// f32 -> bf16 bits, round-to-nearest-even
DI ushort_t f2b(float f) {
    union { float f; uint_t u; } v; v.f = f;
    uint_t u = v.u;
    uint_t r = (u + 0x7fffu + ((u >> 16) & 1u)) >> 16;
    return (ushort_t)r;
}

// fma 8 bf16 feats (packed in uint4) into acc[8]
DI void fma8(float* a, uint4 v, float nm) {
    a[0] += nm * b2f(v.x & 0xffffu); a[1] += nm * b2f(v.x >> 16);
    a[2] += nm * b2f(v.y & 0xffffu); a[3] += nm * b2f(v.y >> 16);
    a[4] += nm * b2f(v.z & 0xffffu); a[5] += nm * b2f(v.z >> 16);
    a[6] += nm * b2f(v.w & 0xffffu); a[7] += nm * b2f(v.w >> 16);
}

// ---------------- P1: bucket histogram (LDS-binned) --------------------------
// Persists this block's per-bucket counts row to hist_g for deterministic scatter.
__global__ __launch_bounds__(1024) void gcn_bhist(
    const int* __restrict__ ei, int* __restrict__ bkt_cnt,
    int* __restrict__ hist_g, int E, int NB)
{
    __shared__ int hist[NBMAX];
    int t = threadIdx.x;
    for (int b = t; b < NB; b += 1024) hist[b] = 0;
    __syncthreads();
    int base = blockIdx.x * 32768;
    int lim = min(32768, E - base);
    for (int i = t; i < lim; i += 1024) {
        int d = ei[(size_t)E + base + i];
        atomicAdd(&hist[d >> 7], 1);
    }
    __syncthreads();
    int* row = hist_g + (size_t)blockIdx.x * NBMAX;
    for (int b = t; b < NB; b += 1024) {
        int c = hist[b];
        row[b] = c;
        if (c) atomicAdd(&bkt_cnt[b], c);
    }
}

// ---------------- P2: scan bucket counts -> bases ----------------------------
__global__ __launch_bounds__(256) void gcn_bscan(
    const int* __restrict__ bkt_cnt, int* __restrict__ bkt_base,
    int* __restrict__ rp, int NB, int N, int E)
{
    __shared__ int lds[256];
    int t = threadIdx.x;
    int v[4]; int s = 0;
    #pragma unroll
    for (int j = 0; j < 4; j++) {
        int b = t * 4 + j;
        v[j] = (b < NB) ? bkt_cnt[b] : 0;
        s += v[j];
    }
    lds[t] = s;
    __syncthreads();
    #pragma unroll
    for (int off = 1; off < 256; off <<= 1) {
        int y = (t >= off) ? lds[t - off] : 0;
        __syncthreads();
        lds[t] += y;
        __syncthreads();
    }
    int run = lds[t] - s;
    #pragma unroll
    for (int j = 0; j < 4; j++) {
        int b = t * 4 + j;
        if (b < NB) bkt_base[b] = run;
        run += v[j];
    }
    if (t == 255) { bkt_base[NB] = E; rp[N] = E; }
}

// ---------------- P2b: rebase per-block rows -> deterministic write bases ----
__global__ __launch_bounds__(256) void gcn_brebase(
    int* __restrict__ hist_g, const int* __restrict__ bkt_base, int NB, int nrows)
{
    int k = blockIdx.x * 256 + threadIdx.x;
    if (k >= NB) return;
    int run = bkt_base[k];
    for (int r = 0; r < nrows; r++) {
        int* p = hist_g + (size_t)r * NBMAX + k;
        int v = *p;
        *p = run;
        run += v;
    }
}

// ---------------- P3: scatter records into bucket regions (no global atomics) -
// record: x = src | (dst&127)<<17 ; y = |w| (f32 bits). Per-edge atomics are LDS.
__global__ __launch_bounds__(1024) void gcn_bscatter(
    const int* __restrict__ ei, const float* __restrict__ ew,
    const int* __restrict__ hist_g, uint2* __restrict__ stage, int E, int NB)
{
    __shared__ int cur[NBMAX];
    int t = threadIdx.x;
    const int* row = hist_g + (size_t)blockIdx.x * NBMAX;
    for (int b = t; b < NB; b += 1024) cur[b] = row[b];
    __syncthreads();
    int base = blockIdx.x * 32768;
    int lim = min(32768, E - base);
    for (int i = t; i < lim; i += 1024) {
        int e = base + i;
        int s = ei[e];
        int d = ei[(size_t)E + e];
        float w = fabsf(ew[e]);
        int pos = atomicAdd(&cur[d >> 7], 1);
        uint2 rec;
        rec.x = (uint_t)s | ((uint_t)(d & 127) << 17);
        rec.y = __float_as_uint(w);
        stage[pos] = rec;
    }
}

// ---------------- P4: per-bucket counting sort by (node, src-chunk) ----------
// Emits rp[n] (node boundaries; global-contiguous across buckets) and dis.
__global__ __launch_bounds__(256) void gcn_bsort(
    const uint2* __restrict__ stage, uint2* __restrict__ edges,
    const int* __restrict__ bkt_base, int* __restrict__ rp,
    float* __restrict__ dis, int N)
{
    int b = blockIdx.x;
    int base = bkt_base[b], end = bkt_base[b + 1];
    int cnte = end - base;
    int n0 = b << 7;
    __shared__ int cnt[NPB * CH];     // 1024 bins
    __shared__ float wsum[NPB];
    __shared__ int scn[256];
    __shared__ int cur[NPB * CH];
    int t = threadIdx.x;
    for (int i = t; i < NPB * CH; i += 256) cnt[i] = 0;
    if (t < NPB) wsum[t] = 0.0f;
    __syncthreads();
    for (int i = t; i < cnte; i += 256) {
        uint2 r = stage[base + i];
        int dl = (r.x >> 17) & 127;
        int ch = (r.x & 0x1FFFF) >> 14;
        atomicAdd(&cnt[dl * CH + ch], 1);
        atomicAdd(&wsum[dl], __uint_as_float(r.y));
    }
    __syncthreads();
    int v0 = cnt[t * 4], v1 = cnt[t * 4 + 1], v2 = cnt[t * 4 + 2], v3 = cnt[t * 4 + 3];
    int s = v0 + v1 + v2 + v3;
    scn[t] = s;
    __syncthreads();
    #pragma unroll
    for (int off = 1; off < 256; off <<= 1) {
        int y = (t >= off) ? scn[t - off] : 0;
        __syncthreads();
        scn[t] += y;
        __syncthreads();
    }
    int e0 = scn[t] - s;
    int e1 = e0 + v0, e2 = e1 + v1, e3 = e2 + v2;
    cur[t * 4]     = base + e0;
    cur[t * 4 + 1] = base + e1;
    cur[t * 4 + 2] = base + e2;
    cur[t * 4 + 3] = base + e3;
    // node dl's start = prefix of bin dl*CH (CH=8 -> bin 8dl, thread 2dl, j=0)
    if ((t & 1) == 0) {
        int dl = t >> 1;
        int n = n0 + dl;
        if (n < N) {
            rp[n] = base + e0;
            dis[n] = rsqrtf(wsum[dl] + 1.0f);
        }
    }
    __syncthreads();
    for (int i = t; i < cnte; i += 256) {
        uint2 r = stage[base + i];
        int dl = (r.x >> 17) & 127;
        int ch = (r.x & 0x1FFFF) >> 14;
        int pos = atomicAdd(&cur[dl * CH + ch], 1);
        edges[pos] = r;
    }
}

// ---------------- weight transpose + bf16 convert (once per call, tiny) -------
__global__ __launch_bounds__(256) void gcn_wt(
    const float* __restrict__ W1, const float* __restrict__ W2,
    const float* __restrict__ W3,
    ushort_t* __restrict__ Wt1, ushort_t* __restrict__ Wt2,
    ushort_t* __restrict__ Wt3)
{
    int i = blockIdx.x * 256 + threadIdx.x;
    if (i < 96 * 128) {                       // layer 1: Wt1[96][128]
        int n = i / 128, k = i % 128;
        Wt1[i] = f2b(W1[k * 96 + n]);
    }
    if (i < 96 * 96) {                        // layer 2: Wt2[96][96]
        int n = i / 96, k = i % 96;
        Wt2[i] = f2b(W2[k * 96 + n]);
    }
    if (i < 32 * 96) {                        // layer 3: Wt3[32][96], pad rows 30,31
        int n = i / 96, k = i % 96;
        Wt3[i] = f2b((n < 30) ? W3[k * 30 + n] : 0.0f);
    }
}

// ---------------- MFMA GEMM: Y[row,:] = dis[row] * (X[row,:] @ W) ------------
template<int K, int FOUT, int NTR, int FOUTP, bool XF32>
__global__ __launch_bounds__(256) void gcn_gemm_mfma(
    const void* __restrict__ Xv, const ushort_t* __restrict__ Wt,
    const float* __restrict__ dis, ushort_t* __restrict__ Y, int N)
{
    constexpr int KS = K + 8;
    constexpr int KT = K / 32;
    constexpr int NT = NTR / 16;
    __shared__ ushort_t xs[64 * KS];
    __shared__ ushort_t ws[NTR * KS];

    int t = threadIdx.x;
    int mbase = blockIdx.x * 64;

    {
        constexpr int TOT = NTR * (K / 8);
        const uint4* wg = (const uint4*)Wt;
        for (int i = t; i < TOT; i += 256) {
            int r = i / (K / 8), c8 = i % (K / 8);
            *(uint4*)(ws + r * KS + c8 * 8) = wg[i];
        }
    }
    if (XF32) {
        const float* X = (const float*)Xv;
        constexpr int TOT = 64 * (K / 4);
        for (int i = t; i < TOT; i += 256) {
            int row = i / (K / 4), c4 = i % (K / 4);
            int rg = mbase + row; if (rg >= N) rg = N - 1;
            float4 v = *(const float4*)(X + (size_t)rg * K + c4 * 4);
            uint2 pv;
            pv.x = (uint_t)f2b(v.x) | ((uint_t)f2b(v.y) << 16);
            pv.y = (uint_t)f2b(v.z) | ((uint_t)f2b(v.w) << 16);
            *(uint2*)(xs + row * KS + c4 * 4) = pv;
        }
    } else {
        const ushort_t* X = (const ushort_t*)Xv;
        constexpr int TOT = 64 * (K / 8);
        for (int i = t; i < TOT; i += 256) {
            int row = i / (K / 8), c8 = i % (K / 8);
            int rg = mbase + row; if (rg >= N) rg = N - 1;
            *(uint4*)(xs + row * KS + c8 * 8) = *(const uint4*)(X + (size_t)rg * K + c8 * 8);
        }
    }
    __syncthreads();

    int wave = t >> 6;
    int lane = t & 63;
    int l15 = lane & 15, quad = lane >> 4;

    bf16x8 af[KT];
    #pragma unroll
    for (int kt = 0; kt < KT; kt++)
        af[kt] = *(const bf16x8*)(xs + (wave * 16 + l15) * KS + kt * 32 + quad * 8);

    floatx4 acc[NT];
    #pragma unroll
    for (int nt = 0; nt < NT; nt++) acc[nt] = (floatx4){0.f, 0.f, 0.f, 0.f};

    #pragma unroll
    for (int nt = 0; nt < NT; nt++) {
        #pragma unroll
        for (int kt = 0; kt < KT; kt++) {
            bf16x8 bfr = *(const bf16x8*)(ws + (nt * 16 + l15) * KS + kt * 32 + quad * 8);
            acc[nt] = __builtin_amdgcn_mfma_f32_16x16x32_bf16(af[kt], bfr, acc[nt], 0, 0, 0);
        }
    }

    float dsc[4];
    #pragma unroll
    for (int r = 0; r < 4; r++) {
        int row = mbase + wave * 16 + quad * 4 + r;
        dsc[r] = (row < N) ? dis[row] : 0.0f;
    }
    #pragma unroll
    for (int nt = 0; nt < NT; nt++) {
        int col = nt * 16 + l15;
        #pragma unroll
        for (int r = 0; r < 4; r++) {
            int row = mbase + wave * 16 + quad * 4 + r;
            if (row < N) {
                float v = (col < FOUT) ? acc[nt][r] * dsc[r] : 0.0f;
                Y[(size_t)row * FOUTP + col] = f2b(v);
            }
        }
    }
}

// ---------------- aggregation: oversubscribed, 8-wide MLP ---------------------
// R6 structure (max wave parallelism was the binding constraint: R6 74% occ /
// 113us vs R9 30% occ / 202us, both latency-bound) with 8 independent
// record+gather chains in flight per thread.
// XWS = dis-scaled xw. H[n] = relu(b + dis[n]*(sum_e w*XWS[src] + XWS[n])).
template<int FOUT, int FOUTP, int LPN, int BLK>
__global__ __launch_bounds__(BLK) void gcn_agg(
    const ushort_t* __restrict__ XWS, const int* __restrict__ rp,
    const uint2* __restrict__ edges,
    const float* __restrict__ dis, const float* __restrict__ bias,
    ushort_t* __restrict__ H, int N)
{
    constexpr int NC = FOUTP / 8;           // uint4 per row (== LPN)
    int n = blockIdx.x * (BLK / LPN) + threadIdx.x / LPN;
    int c = threadIdx.x % LPN;
    if (n >= N) return;
    const uint4* xwc = (const uint4*)XWS;
    const u64_t* ed64 = (const u64_t*)edges;

    int beg = rp[n], end = rp[n + 1];
    float a[8];
    #pragma unroll
    for (int j = 0; j < 8; j++) a[j] = 0.0f;

    int e = beg;
    for (; e + 8 <= end; e += 8) {
        u64_t r0 = __builtin_nontemporal_load(ed64 + e);
        u64_t r1 = __builtin_nontemporal_load(ed64 + e + 1);
        u64_t r2 = __builtin_nontemporal_load(ed64 + e + 2);
        u64_t r3 = __builtin_nontemporal_load(ed64 + e + 3);
        u64_t r4 = __builtin_nontemporal_load(ed64 + e + 4);
        u64_t r5 = __builtin_nontemporal_load(ed64 + e + 5);
        u64_t r6 = __builtin_nontemporal_load(ed64 + e + 6);
        u64_t r7 = __builtin_nontemporal_load(ed64 + e + 7);
        uint4 v0 = xwc[(size_t)((uint_t)r0 & 0x1FFFF) * NC + c];
        uint4 v1 = xwc[(size_t)((uint_t)r1 & 0x1FFFF) * NC + c];
        uint4 v2 = xwc[(size_t)((uint_t)r2 & 0x1FFFF) * NC + c];
        uint4 v3 = xwc[(size_t)((uint_t)r3 & 0x1FFFF) * NC + c];
        uint4 v4 = xwc[(size_t)((uint_t)r4 & 0x1FFFF) * NC + c];
        uint4 v5 = xwc[(size_t)((uint_t)r5 & 0x1FFFF) * NC + c];
        uint4 v6 = xwc[(size_t)((uint_t)r6 & 0x1FFFF) * NC + c];
        uint4 v7 = xwc[(size_t)((uint_t)r7 & 0x1FFFF) * NC + c];
        fma8(a, v0, __uint_as_float((uint_t)(r0 >> 32)));
        fma8(a, v1, __uint_as_float((uint_t)(r1 >> 32)));
        fma8(a, v2, __uint_as_float((uint_t)(r2 >> 32)));
        fma8(a, v3, __uint_as_float((uint_t)(r3 >> 32)));
        fma8(a, v4, __uint_as_float((uint_t)(r4 >> 32)));
        fma8(a, v5, __uint_as_float((uint_t)(r5 >> 32)));
        fma8(a, v6, __uint_as_float((uint_t)(r6 >> 32)));
        fma8(a, v7, __uint_as_float((uint_t)(r7 >> 32)));
    }
    for (; e + 4 <= end; e += 4) {
        u64_t r0 = __builtin_nontemporal_load(ed64 + e);
        u64_t r1 = __builtin_nontemporal_load(ed64 + e + 1);
        u64_t r2 = __builtin_nontemporal_load(ed64 + e + 2);
        u64_t r3 = __builtin_nontemporal_load(ed64 + e + 3);
        uint4 v0 = xwc[(size_t)((uint_t)r0 & 0x1FFFF) * NC + c];
        uint4 v1 = xwc[(size_t)((uint_t)r1 & 0x1FFFF) * NC + c];
        uint4 v2 = xwc[(size_t)((uint_t)r2 & 0x1FFFF) * NC + c];
        uint4 v3 = xwc[(size_t)((uint_t)r3 & 0x1FFFF) * NC + c];
        fma8(a, v0, __uint_as_float((uint_t)(r0 >> 32)));
        fma8(a, v1, __uint_as_float((uint_t)(r1 >> 32)));
        fma8(a, v2, __uint_as_float((uint_t)(r2 >> 32)));
        fma8(a, v3, __uint_as_float((uint_t)(r3 >> 32)));
    }
    for (; e < end; e++) {
        u64_t r0 = __builtin_nontemporal_load(ed64 + e);
        uint4 v0 = xwc[(size_t)((uint_t)r0 & 0x1FFFF) * NC + c];
        fma8(a, v0, __uint_as_float((uint_t)(r0 >> 32)));
    }

    uint4 sv = xwc[(size_t)n * NC + c];
    fma8(a, sv, 1.0f);                 // + XWS[n]
    float d = dis[n];
    int f0 = c * 8;
    uint_t o[4];
    #pragma unroll
    for (int p = 0; p < 4; p++) {
        float rA = (f0 + 2 * p     < FOUT) ? fmaxf(a[2 * p]     * d + bias[f0 + 2 * p],     0.f) : 0.f;
        float rB = (f0 + 2 * p + 1 < FOUT) ? fmaxf(a[2 * p + 1] * d + bias[f0 + 2 * p + 1], 0.f) : 0.f;
        o[p] = (uint_t)f2b(rA) | ((uint_t)f2b(rB) << 16);
    }
    uint4 ov = {o[0], o[1], o[2], o[3]};
    *((uint4*)H + (size_t)n * NC + c) = ov;
}

// ---------------- mean-pool per graph + final linear + softmax ----------------
__global__ __launch_bounds__(256) void gcn_pool(
    const ushort_t* __restrict__ H, const int* __restrict__ batch,
    const float* __restrict__ Wf, const float* __restrict__ bf_,
    float* __restrict__ out, int N)
{
    __shared__ float pool[32];
    int g = blockIdx.x;
    int t = threadIdx.x;

    int lo = 0, hi = N;
    while (lo < hi) { int mid = (lo + hi) >> 1; if (batch[mid] < g) lo = mid + 1; else hi = mid; }
    int start = lo;
    lo = 0; hi = N;
    while (lo < hi) { int mid = (lo + hi) >> 1; if (batch[mid] < g + 1) lo = mid + 1; else hi = mid; }
    int end = lo;

    float acc[32];
    #pragma unroll
    for (int f = 0; f < 32; f++) acc[f] = 0.0f;
    for (int i = start + t; i < end; i += 256) {
        const uint2* hr = (const uint2*)H + (size_t)i * 8;
        #pragma unroll
        for (int q = 0; q < 8; q++) {
            uint2 v = hr[q];
            acc[4 * q + 0] += b2f(v.x & 0xffffu);
            acc[4 * q + 1] += b2f(v.x >> 16);
            acc[4 * q + 2] += b2f(v.y & 0xffffu);
            acc[4 * q + 3] += b2f(v.y >> 16);
        }
    }
    #pragma unroll
    for (int f = 0; f < 32; f++) {
        float v = acc[f];
        v += __shfl_down(v, 32, 64);
        v += __shfl_down(v, 16, 64);
        v += __shfl_down(v, 8, 64);
        v += __shfl_down(v, 4, 64);
        v += __shfl_down(v, 2, 64);
        v += __shfl_down(v, 1, 64);
        acc[f] = v;
    }
    if (t < 32) pool[t] = 0.0f;
    __syncthreads();
    if ((t & 63) == 0) {
        #pragma unroll
        for (int f = 0; f < 30; f++) atomicAdd(&pool[f], acc[f]);
    }
    __syncthreads();
    if (t == 0) {
        float inv = 1.0f / fmaxf((float)(end - start), 1.0f);
        float lg[10];
        #pragma unroll
        for (int j = 0; j < 10; j++) lg[j] = bf_[j];
        for (int f = 0; f < 30; f++) {
            float p = pool[f] * inv;
            #pragma unroll
            for (int j = 0; j < 10; j++) lg[j] += p * Wf[f * 10 + j];
        }
        float m = lg[0];
        #pragma unroll
        for (int j = 1; j < 10; j++) m = fmaxf(m, lg[j]);
        float s = 0.f;
        #pragma unroll
        for (int j = 0; j < 10; j++) { lg[j] = __expf(lg[j] - m); s += lg[j]; }
        float is = 1.0f / s;
        #pragma unroll
        for (int j = 0; j < 10; j++) out[g * 10 + j] = lg[j] * is;
    }
}

extern "C" void kernel_launch(void* const* d_in, const int* in_sizes, int n_in,
                              void* d_out, int out_size, void* d_ws, size_t ws_size,
                              hipStream_t stream) {
    (void)n_in; (void)out_size; (void)ws_size;
    const float* x   = (const float*)d_in[0];
    const int*   ei  = (const int*)d_in[1];
    const float* ew  = (const float*)d_in[2];
    const int*   bat = (const int*)d_in[3];
    const float* W1  = (const float*)d_in[4];
    const float* b1  = (const float*)d_in[5];
    const float* W2  = (const float*)d_in[6];
    const float* b2  = (const float*)d_in[7];
    const float* W3  = (const float*)d_in[8];
    const float* b3  = (const float*)d_in[9];
    const float* Wf  = (const float*)d_in[10];
    const float* bf_ = (const float*)d_in[11];
    float* out = (float*)d_out;

    const int N = in_sizes[3];       // 100000
    const int E = in_sizes[2];       // 3200000
    const int NB = (N + NPB - 1) / NPB;   // 782
    const int gB = (E + 32767) / 32768;   // 98

    char* wsb = (char*)d_ws;
    size_t o = 0;
    auto take = [&](size_t bytes) -> char* {
        char* p = wsb + o;
        o += (bytes + 255) & ~(size_t)255;
        return p;
    };
    int*      bkt_cnt    = (int*)take(NBMAX * 4);             // zeroed each call
    int*      bkt_base   = (int*)take((NBMAX + 1) * 4);
    int*      hist_g     = (int*)take((size_t)gB * NBMAX * 4);
    int*      rp         = (int*)take((size_t)(N + 1) * 4);
    float*    dis        = (float*)take((size_t)N * 4);
    uint2*    stage      = (uint2*)take((size_t)E * 8);       // dead after bsort; xw aliases it
    uint2*    edges      = (uint2*)take((size_t)E * 8);
    ushort_t* h          = (ushort_t*)take((size_t)N * 96 * 2);
    ushort_t* Wt1        = (ushort_t*)take(96 * 128 * 2);
    ushort_t* Wt2        = (ushort_t*)take(96 * 96 * 2);
    ushort_t* Wt3        = (ushort_t*)take(32 * 96 * 2);
    ushort_t* xw         = (ushort_t*)stage;                  // alias (E*8 >= N*96*2)

    const int gM = (N + 63) / 64;

    hipMemsetAsync(bkt_cnt, 0, NBMAX * 4, stream);

    // CSR build: hist (+rows) -> scan -> rebase -> deterministic scatter -> sort
    gcn_bhist<<<gB, 1024, 0, stream>>>(ei, bkt_cnt, hist_g, E, NB);
    gcn_wt<<<48, 256, 0, stream>>>(W1, W2, W3, Wt1, Wt2, Wt3);
    gcn_bscan<<<1, 256, 0, stream>>>(bkt_cnt, bkt_base, rp, NB, N, E);
    gcn_brebase<<<(NB + 255) / 256, 256, 0, stream>>>(hist_g, bkt_base, NB, gB);
    gcn_bscatter<<<gB, 1024, 0, stream>>>(ei, ew, hist_g, stage, E, NB);
    gcn_bsort<<<NB, 256, 0, stream>>>(stage, edges, bkt_base, rp, dis, N);

    // agg grids: oversubscribed (max wave parallelism)
    const int gA96 = (N + 15) / 16;    // 6250 blocks x 3 waves
    const int gA32 = (N + 63) / 64;    // 1563 blocks x 4 waves

    // layer 1: x[.,128](fp32) -> xws[.,96](bf16, dis-scaled) -> h[.,96](bf16)
    gcn_gemm_mfma<128, 96, 96, 96, true><<<gM, 256, 0, stream>>>(x, Wt1, dis, xw, N);
    gcn_agg<96, 96, 12, 192><<<gA96, 192, 0, stream>>>(xw, rp, edges, dis, b1, h, N);

    // layer 2
    gcn_gemm_mfma<96, 96, 96, 96, false><<<gM, 256, 0, stream>>>(h, Wt2, dis, xw, N);
    gcn_agg<96, 96, 12, 192><<<gA96, 192, 0, stream>>>(xw, rp, edges, dis, b2, h, N);

    // layer 3 (FOUT=30 padded to 32)
    gcn_gemm_mfma<96, 30, 32, 32, false><<<gM, 256, 0, stream>>>(h, Wt3, dis, xw, N);
    gcn_agg<30, 32, 4, 256><<<gA32, 256, 0, stream>>>(xw, rp, edges, dis, b3, h, N);

    // mean pool + classifier + softmax
    gcn_pool<<<256, 256, 0, stream>>>(h, bat, Wf, bf_, out, N);
}